// Round 1
// baseline (347.920 us; speedup 1.0000x reference)
//
#include <hip/hip_runtime.h>
#include <hip/hip_bf16.h>

typedef __bf16 bf16x8 __attribute__((ext_vector_type(8)));
typedef float  f32x4  __attribute__((ext_vector_type(4)));

#define LAYERS 16
#define DIM 64
#define NHID 256
#define BATCH 32768
#define MTILE 64
#define NBLOCKS (BATCH / MTILE)   // 512

// packed weight sizes in bf16 elements
#define W0P_PER 16384             // per (net,layer): 16 ntiles * 2 ktiles * 512
#define W1P_PER 65536             // 16 ntiles * 8 ktiles * 512
#define W2P_PER 16384             // 4 ntiles * 8 ktiles * 512
#define W0P_TOT (32 * W0P_PER)    // 524288
#define W1P_TOT (32 * W1P_PER)    // 2097152
#define W2P_TOT (32 * W2P_PER)    // 524288
#define PACK_TOT (W0P_TOT + W1P_TOT + W2P_TOT)  // 3145728 bf16 = 6.29 MB

// ---------------------------------------------------------------------------
// Pack kernel: masked weights -> bf16, laid out in MFMA B-fragment order:
// per (net, layer, gemm): [ntile][ktile][lane(64)][j(8)], element =
// W[n][k+j]*M[n][k+j] with n = ntile*16 + (lane&15), k = ktile*32 + (lane>>4)*8.
// One thread writes one 8-elem fragment row (16 B).
// ---------------------------------------------------------------------------
__global__ __launch_bounds__(256) void pack_weights(
    const float* __restrict__ lW0, const float* __restrict__ lW1, const float* __restrict__ lW2,
    const float* __restrict__ sW0, const float* __restrict__ sW1, const float* __restrict__ sW2,
    const float* __restrict__ M0,  const float* __restrict__ M1,  const float* __restrict__ M2,
    __bf16* __restrict__ ws)
{
    const long i = ((long)blockIdx.x * 256 + threadIdx.x) * 8;  // elem base
    const float* W; const float* M; long src;
    if (i < W0P_TOT) {
        int netl = (int)(i / W0P_PER), rem = (int)(i % W0P_PER);
        int net = netl >> 4, l = netl & 15;
        int nt = rem >> 10, kt = (rem >> 9) & 1, lane = (rem >> 3) & 63;
        int n = nt * 16 + (lane & 15), k = kt * 32 + (lane >> 4) * 8;
        W = net ? sW0 : lW0; M = M0;
        src = (long)(l * 256 + n) * 64 + k;
    } else if (i < W0P_TOT + W1P_TOT) {
        long r = i - W0P_TOT;
        int netl = (int)(r / W1P_PER), rem = (int)(r % W1P_PER);
        int net = netl >> 4, l = netl & 15;
        int nt = rem >> 12, kt = (rem >> 9) & 7, lane = (rem >> 3) & 63;
        int n = nt * 16 + (lane & 15), k = kt * 32 + (lane >> 4) * 8;
        W = net ? sW1 : lW1; M = M1;
        src = (long)(l * 256 + n) * 256 + k;
    } else {
        long r = i - W0P_TOT - W1P_TOT;
        int netl = (int)(r / W2P_PER), rem = (int)(r % W2P_PER);
        int net = netl >> 4, l = netl & 15;
        int nt = rem >> 12, kt = (rem >> 9) & 7, lane = (rem >> 3) & 63;
        int n = nt * 16 + (lane & 15), k = kt * 32 + (lane >> 4) * 8;
        W = net ? sW2 : lW2; M = M2;
        src = (long)(l * 64 + n) * 256 + k;
    }
    f32x4 wa = *(const f32x4*)(W + src);
    f32x4 wb = *(const f32x4*)(W + src + 4);
    f32x4 ma = *(const f32x4*)(M + src);
    f32x4 mb = *(const f32x4*)(M + src + 4);
    bf16x8 o;
    o[0] = (__bf16)(wa[0] * ma[0]); o[1] = (__bf16)(wa[1] * ma[1]);
    o[2] = (__bf16)(wa[2] * ma[2]); o[3] = (__bf16)(wa[3] * ma[3]);
    o[4] = (__bf16)(wb[0] * mb[0]); o[5] = (__bf16)(wb[1] * mb[1]);
    o[6] = (__bf16)(wb[2] * mb[2]); o[7] = (__bf16)(wb[3] * mb[3]);
    *(bf16x8*)(ws + i) = o;
}

// ---------------------------------------------------------------------------
// Main flow kernel. One block = 64 rows, 4 waves, all 16 layers in-block.
// y lives in fp32 registers in MFMA C-layout (wave w owns cols [16w,16w+16)).
// h0/h1 bf16 in LDS (padded stride). Weight B-fragments read straight from
// the packed global array (each fragment exactly once per block).
// ---------------------------------------------------------------------------
__global__ __launch_bounds__(256, 2) void flow_kernel(
    const float* __restrict__ u,
    const __bf16* __restrict__ wp,
    const float* __restrict__ lb0, const float* __restrict__ lb1, const float* __restrict__ lb2,
    const float* __restrict__ sb0, const float* __restrict__ sb1, const float* __restrict__ sb2,
    float* __restrict__ out)
{
    __shared__ __bf16 ybf[MTILE][72];    // stride 144B (36 words -> 2-way, free)
    __shared__ __bf16 buf1[MTILE][264];  // stride 528B (132 words -> 2-way, free)
    __shared__ __bf16 buf2[MTILE][264];

    const int tid  = threadIdx.x;
    const int wave = tid >> 6;
    const int lane = tid & 63;
    const int quad = lane >> 4;
    const int l16  = lane & 15;
    const int blk  = blockIdx.x;

    const __bf16* w0p = wp;
    const __bf16* w1p = wp + W0P_TOT;
    const __bf16* w2p = wp + W0P_TOT + W1P_TOT;

    // y in C-layout: y[mt][r] = row (blk*64 + mt*16 + quad*4 + r), col (wave*16 + l16)
    float y[4][4];
    #pragma unroll
    for (int mt = 0; mt < 4; ++mt)
        #pragma unroll
        for (int r = 0; r < 4; ++r) {
            int row = blk * MTILE + mt * 16 + quad * 4 + r;
            y[mt][r] = u[row * DIM + wave * 16 + l16];
        }

    for (int l = 0; l < LAYERS; ++l) {
        // stage y -> bf16 A-operand buffer
        #pragma unroll
        for (int mt = 0; mt < 4; ++mt)
            #pragma unroll
            for (int r = 0; r < 4; ++r)
                ybf[mt * 16 + quad * 4 + r][wave * 16 + l16] = (__bf16)y[mt][r];
        __syncthreads();  // B1

        float locr[4][4], scr[4][4];

        #pragma unroll
        for (int net = 0; net < 2; ++net) {
            const __bf16* w0b = w0p + (long)(net * 16 + l) * W0P_PER;
            const __bf16* w1b = w1p + (long)(net * 16 + l) * W1P_PER;
            const __bf16* w2b = w2p + (long)(net * 16 + l) * W2P_PER;
            const float* b0 = (net ? sb0 : lb0) + l * 256;
            const float* b1 = (net ? sb1 : lb1) + l * 256;
            const float* b2 = (net ? sb2 : lb2) + l * 64;

            // ---- G1: [64x64] @ W0^T -> buf1 [64x256]; wave owns 4 n-tiles ----
            {
                f32x4 acc[4][4];
                #pragma unroll
                for (int mt = 0; mt < 4; ++mt)
                    #pragma unroll
                    for (int nt = 0; nt < 4; ++nt)
                        acc[mt][nt] = (f32x4){0.f, 0.f, 0.f, 0.f};
                #pragma unroll
                for (int kt = 0; kt < 2; ++kt) {
                    bf16x8 a[4], b[4];
                    #pragma unroll
                    for (int mt = 0; mt < 4; ++mt)
                        a[mt] = *(const bf16x8*)&ybf[mt * 16 + l16][kt * 32 + quad * 8];
                    #pragma unroll
                    for (int nt = 0; nt < 4; ++nt)
                        b[nt] = *(const bf16x8*)(w0b + (long)((wave * 4 + nt) * 2 + kt) * 512 + lane * 8);
                    #pragma unroll
                    for (int mt = 0; mt < 4; ++mt)
                        #pragma unroll
                        for (int nt = 0; nt < 4; ++nt)
                            acc[mt][nt] = __builtin_amdgcn_mfma_f32_16x16x32_bf16(a[mt], b[nt], acc[mt][nt], 0, 0, 0);
                }
                #pragma unroll
                for (int nt = 0; nt < 4; ++nt) {
                    float bias = b0[(wave * 4 + nt) * 16 + l16];
                    #pragma unroll
                    for (int mt = 0; mt < 4; ++mt)
                        #pragma unroll
                        for (int r = 0; r < 4; ++r) {
                            float v = acc[mt][nt][r] + bias;
                            buf1[mt * 16 + quad * 4 + r][(wave * 4 + nt) * 16 + l16] = (__bf16)fmaxf(v, 0.f);
                        }
                }
            }
            __syncthreads();  // h0 ready

            // ---- G2: buf1 [64x256] @ W1^T -> buf2 [64x256] ----
            {
                f32x4 acc[4][4];
                #pragma unroll
                for (int mt = 0; mt < 4; ++mt)
                    #pragma unroll
                    for (int nt = 0; nt < 4; ++nt)
                        acc[mt][nt] = (f32x4){0.f, 0.f, 0.f, 0.f};
                #pragma unroll
                for (int kt = 0; kt < 8; ++kt) {
                    bf16x8 a[4], b[4];
                    #pragma unroll
                    for (int mt = 0; mt < 4; ++mt)
                        a[mt] = *(const bf16x8*)&buf1[mt * 16 + l16][kt * 32 + quad * 8];
                    #pragma unroll
                    for (int nt = 0; nt < 4; ++nt)
                        b[nt] = *(const bf16x8*)(w1b + (long)((wave * 4 + nt) * 8 + kt) * 512 + lane * 8);
                    #pragma unroll
                    for (int mt = 0; mt < 4; ++mt)
                        #pragma unroll
                        for (int nt = 0; nt < 4; ++nt)
                            acc[mt][nt] = __builtin_amdgcn_mfma_f32_16x16x32_bf16(a[mt], b[nt], acc[mt][nt], 0, 0, 0);
                }
                #pragma unroll
                for (int nt = 0; nt < 4; ++nt) {
                    float bias = b1[(wave * 4 + nt) * 16 + l16];
                    #pragma unroll
                    for (int mt = 0; mt < 4; ++mt)
                        #pragma unroll
                        for (int r = 0; r < 4; ++r) {
                            float v = acc[mt][nt][r] + bias;
                            buf2[mt * 16 + quad * 4 + r][(wave * 4 + nt) * 16 + l16] = (__bf16)fmaxf(v, 0.f);
                        }
                }
            }
            __syncthreads();  // h1 ready (also: all buf1 reads done -> next G1 may overwrite)

            // ---- G3: buf2 [64x256] @ W2^T -> wave's 16-col slice, in registers ----
            {
                f32x4 acc[4];
                #pragma unroll
                for (int mt = 0; mt < 4; ++mt)
                    acc[mt] = (f32x4){0.f, 0.f, 0.f, 0.f};
                #pragma unroll
                for (int kt = 0; kt < 8; ++kt) {
                    bf16x8 a[4];
                    bf16x8 b = *(const bf16x8*)(w2b + (long)(wave * 8 + kt) * 512 + lane * 8);
                    #pragma unroll
                    for (int mt = 0; mt < 4; ++mt)
                        a[mt] = *(const bf16x8*)&buf2[mt * 16 + l16][kt * 32 + quad * 8];
                    #pragma unroll
                    for (int mt = 0; mt < 4; ++mt)
                        acc[mt] = __builtin_amdgcn_mfma_f32_16x16x32_bf16(a[mt], b, acc[mt], 0, 0, 0);
                }
                float bias = b2[wave * 16 + l16];
                if (net == 0) {
                    #pragma unroll
                    for (int mt = 0; mt < 4; ++mt)
                        #pragma unroll
                        for (int r = 0; r < 4; ++r)
                            locr[mt][r] = acc[mt][r] + bias;
                } else {
                    #pragma unroll
                    for (int mt = 0; mt < 4; ++mt)
                        #pragma unroll
                        for (int r = 0; r < 4; ++r)
                            scr[mt][r] = acc[mt][r] + bias;
                }
            }
            // no barrier needed after G3 (next G1 writes buf1; all buf1 readers
            // passed the post-G2 barrier; G3 only reads buf2)
        }

        // coupling update, pure registers: y = exp(-sc) * (y - loc)
        #pragma unroll
        for (int mt = 0; mt < 4; ++mt)
            #pragma unroll
            for (int r = 0; r < 4; ++r)
                y[mt][r] = __expf(-scr[mt][r]) * (y[mt][r] - locr[mt][r]);
        // next iteration's ybf write is safe: all ybf readers (G1s) are behind
        // the post-G2 barriers of this layer
    }

    #pragma unroll
    for (int mt = 0; mt < 4; ++mt)
        #pragma unroll
        for (int r = 0; r < 4; ++r) {
            int row = blk * MTILE + mt * 16 + quad * 4 + r;
            out[row * DIM + wave * 16 + l16] = y[mt][r];
        }
}

extern "C" void kernel_launch(void* const* d_in, const int* in_sizes, int n_in,
                              void* d_out, int out_size, void* d_ws, size_t ws_size,
                              hipStream_t stream) {
    const float* u   = (const float*)d_in[0];
    const float* lW0 = (const float*)d_in[1];
    const float* lb0 = (const float*)d_in[2];
    const float* lW1 = (const float*)d_in[3];
    const float* lb1 = (const float*)d_in[4];
    const float* lW2 = (const float*)d_in[5];
    const float* lb2 = (const float*)d_in[6];
    const float* sW0 = (const float*)d_in[7];
    const float* sb0 = (const float*)d_in[8];
    const float* sW1 = (const float*)d_in[9];
    const float* sb1 = (const float*)d_in[10];
    const float* sW2 = (const float*)d_in[11];
    const float* sb2 = (const float*)d_in[12];
    const float* M0  = (const float*)d_in[13];
    const float* M1  = (const float*)d_in[14];
    const float* M2  = (const float*)d_in[15];

    if (ws_size < (size_t)PACK_TOT * sizeof(__bf16)) return;  // workspace too small
    __bf16* ws = (__bf16*)d_ws;

    pack_weights<<<PACK_TOT / 8 / 256, 256, 0, stream>>>(
        lW0, lW1, lW2, sW0, sW1, sW2, M0, M1, M2, ws);
    flow_kernel<<<NBLOCKS, 256, 0, stream>>>(
        u, ws, lb0, lb1, lb2, sb0, sb1, sb2, (float*)d_out);
}